// Round 5
// baseline (73.676 us; speedup 1.0000x reference)
//
#include <hip/hip_runtime.h>
#include <hip/hip_bf16.h>

#define N_CELLS  16384
#define N_SPOTS  4096
#define N_LABELS 512
#define NTHREADS 512
#define CPB      8       // cells per block (main kernel)
#define NPAIR    (CPB/2) // packed-f32 cell pairs
#define TABLE    6144    // padded spot-table capacity (float2)
#define MAXSEG   32      // register-sort capacity per label segment

typedef float v2f __attribute__((ext_vector_type(2)));

#if defined(__has_builtin)
#if __has_builtin(__builtin_amdgcn_exp2f)
#define FAST_EXP2(x) __builtin_amdgcn_exp2f(x)
#else
#define FAST_EXP2(x) exp2f(x)
#endif
#else
#define FAST_EXP2(x) exp2f(x)
#endif

// log2(e)/2 : fold both 1/(2D) and log2(e) into the coordinate prescale
#define HALF_LOG2E 0.72134752044448170f

// ---------------------------------------------------------------------------
// Setup (1 block, 512 threads) — identical to rounds 2-4.
// ---------------------------------------------------------------------------
__global__ __launch_bounds__(512) void build_kernel(
    const float* __restrict__ ex, const float* __restrict__ ey,
    const int* __restrict__ labels, const float* __restrict__ dconst,
    float2* __restrict__ table, int* __restrict__ meta)
{
    __shared__ unsigned short s_lab[N_SPOTS];   // 8 KB
    __shared__ int s_c[N_LABELS];
    __shared__ int s_h2[128];
    __shared__ int s_suf[128];                  // suffix sums of h2
    __shared__ int s_pcw[32 * 8];               // per-(count,wave) label counts
    __shared__ int s_rlab[N_LABELS];
    __shared__ int s_rcnt[N_LABELS];
    __shared__ int s_wmax[8];
    __shared__ int s_wbase[8];
    __shared__ int s_cur[N_LABELS];
    __shared__ unsigned short s_idx[TABLE];     // 12 KB

    const int t = threadIdx.x;
    const int lane = t & 63, w = t >> 6;

    s_c[t] = 0;
    if (t < 128) s_h2[t] = 0;
    for (int i = t; i < N_SPOTS; i += NTHREADS) s_lab[i] = (unsigned short)labels[i];
    __syncthreads();

    for (int i = t; i < N_SPOTS; i += NTHREADS) atomicAdd(&s_c[s_lab[i]], 1);
    __syncthreads();

    const int myc  = s_c[t];
    const int mycc = myc < 127 ? myc : 127;
    atomicAdd(&s_h2[mycc], 1);
    __syncthreads();

    if (t < 128) s_suf[t] = s_h2[t];
    __syncthreads();
    for (int off = 1; off < 128; off <<= 1) {
        int add = (t < 128 && t + off < 128) ? s_suf[t + off] : 0;
        __syncthreads();
        if (t < 128) s_suf[t] += add;
        __syncthreads();
    }

    int pos_w = 0;
    for (int v = 0; v < 32; ++v) {
        unsigned long long mask = __ballot(myc == v);
        if (myc == v) pos_w = __popcll(mask & ((1ull << lane) - 1ull));
        if (lane == 0) s_pcw[v * 8 + w] = __popcll(mask);
    }
    __syncthreads();
    int pos;
    if (myc < 32) {
        pos = pos_w;
        for (int w2 = 0; w2 < w; ++w2) pos += s_pcw[myc * 8 + w2];
    } else {
        pos = 0;
        for (int j = 0; j < t; ++j) pos += (s_c[j] == myc) ? 1 : 0;
    }
    const int r = ((myc < 127) ? s_suf[myc + 1] : 0) + pos;
    s_rlab[r] = t;
    s_rcnt[r] = myc;
    __syncthreads();

    int v = s_rcnt[t];
    #pragma unroll
    for (int off = 32; off; off >>= 1) { int o = __shfl_xor(v, off); v = v > o ? v : o; }
    if (lane == 0) s_wmax[w] = v;
    __syncthreads();
    if (t == 0) {
        int pb = 0;
        #pragma unroll
        for (int w2 = 0; w2 < 8; ++w2) { s_wbase[w2] = 64 * pb; pb += s_wmax[w2]; }
    }
    __syncthreads();

    const int mytrip    = s_wmax[w];
    const int wbase     = s_wbase[w];
    const int lin_start = wbase + lane * mytrip;

    for (int i = t; i < TABLE; i += NTHREADS) s_idx[i] = 0xFFFFu;
    s_cur[s_rlab[t]] = lin_start;
    __syncthreads();

    for (int i = t; i < N_SPOTS; i += NTHREADS) {
        int l = s_lab[i];
        int p = atomicAdd(&s_cur[l], 1);
        if (p < TABLE) s_idx[p] = (unsigned short)i;
    }
    __syncthreads();

    const float Dv = dconst[0];
    const float sc = sqrtf(HALF_LOG2E / Dv);

    if (mytrip <= MAXSEG) {
        unsigned key[MAXSEG];
        #pragma unroll
        for (int k = 0; k < MAXSEG; ++k)
            key[k] = (k < mytrip && lin_start + k < TABLE)
                         ? (unsigned)s_idx[lin_start + k] : 0xFFFFu;
        #pragma unroll
        for (int kk = 2; kk <= MAXSEG; kk <<= 1) {
            #pragma unroll
            for (int j = kk >> 1; j > 0; j >>= 1) {
                #pragma unroll
                for (int i = 0; i < MAXSEG; ++i) {
                    int ixj = i ^ j;
                    if (ixj > i) {
                        unsigned a = key[i], b = key[ixj];
                        unsigned lo = a < b ? a : b, hi = a < b ? b : a;
                        if ((i & kk) == 0) { key[i] = lo; key[ixj] = hi; }
                        else               { key[i] = hi; key[ixj] = lo; }
                    }
                }
            }
        }
        #pragma unroll
        for (int k = 0; k < MAXSEG; ++k) {
            if (k < mytrip) {
                int idx = wbase + k * 64 + lane;
                if (idx < TABLE) {
                    unsigned s = key[k];
                    float2 val = (s == 0xFFFFu) ? make_float2(1e8f, 0.f)
                                                : make_float2(ex[s] * sc, ey[s] * sc);
                    table[idx] = val;
                }
            }
        }
    } else {
        for (int a = lin_start + 1; a < lin_start + mytrip && a < TABLE; ++a) {
            unsigned short kv = s_idx[a];
            int b = a - 1;
            while (b >= lin_start && s_idx[b] > kv) { s_idx[b + 1] = s_idx[b]; --b; }
            s_idx[b + 1] = kv;
        }
        for (int k = 0; k < mytrip; ++k) {
            int idx = wbase + k * 64 + lane;
            if (idx < TABLE && lin_start + k < TABLE) {
                unsigned s = s_idx[lin_start + k];
                float2 val = (s == 0xFFFFu) ? make_float2(1e8f, 0.f)
                                            : make_float2(ex[s] * sc, ey[s] * sc);
                table[idx] = val;
            }
        }
    }

    meta[t]                = wbase;
    meta[NTHREADS + t]     = mytrip;
    meta[2 * NTHREADS + t] = s_rlab[t];
    meta[3 * NTHREADS + t] = s_rcnt[t];
}

// ---------------------------------------------------------------------------
// Main — identical to round 4. (Idempotent: safe to launch multiple times.)
// ---------------------------------------------------------------------------
__global__ __launch_bounds__(512) void diffusion_main_kernel(
    const float* __restrict__ z, const float* __restrict__ dconst,
    const v2f* __restrict__ table, const int* __restrict__ meta,
    float* __restrict__ out)
{
    __shared__ float tr[CPB * N_LABELS];   // 16 KB transpose buffer

    const int t = threadIdx.x;
    const int lane = t & 63, w = t >> 6;

    const int c = (w + (int)blockIdx.x) & 7;
    const int u = c * 64 + lane;

    const int wbase  = __builtin_amdgcn_readfirstlane(meta[u]);
    const int trip   = __builtin_amdgcn_readfirstlane(meta[NTHREADS + u]);
    const int my_lab = meta[2 * NTHREADS + u];
    const float cntf = (float)meta[3 * NTHREADS + u];

    const float D    = dconst[0];
    const float sc   = sqrtf(HALF_LOG2E / D);
    const float norm = 1.0f / (6.28318530717958647f * D);
    const float base = cntf * 1e-12f;      // hoisted UNDERFLOW_NU

    const int cell0 = blockIdx.x * CPB;
    v2f zxn[NPAIR], zyn[NPAIR], acc[NPAIR];
    #pragma unroll
    for (int j = 0; j < NPAIR; ++j) {
        zxn[j] = (v2f){ -z[2 * (cell0 + 2 * j)]     * sc,
                        -z[2 * (cell0 + 2 * j + 1)] * sc };
        zyn[j] = (v2f){ -z[2 * (cell0 + 2 * j) + 1]     * sc,
                        -z[2 * (cell0 + 2 * j + 1) + 1] * sc };
        acc[j] = (v2f){0.f, 0.f};
    }

    const v2f* seg = table + wbase + lane;
    if (trip > 0) {
        v2f xy = seg[0];
        for (int p = 0; p < trip; ++p) {
            int pn = (p + 1 < trip) ? p + 1 : p;
            v2f nxt = seg[(size_t)pn * 64];
            v2f xx = (v2f){xy.x, xy.x};
            v2f yy = (v2f){xy.y, xy.y};
            #pragma unroll
            for (int j = 0; j < NPAIR; ++j) {
                v2f dx = xx + zxn[j];
                v2f dy = yy + zyn[j];
                v2f m  = dy * dy;
                v2f nd2 = __builtin_elementwise_fma(-dx, dx, -m);
                v2f e  = (v2f){ FAST_EXP2(nd2.x), FAST_EXP2(nd2.y) };
                acc[j] += e;
            }
            xy = nxt;
        }
    }

    #pragma unroll
    for (int j = 0; j < NPAIR; ++j) {
        tr[(2 * j)     * N_LABELS + my_lab] = fmaf(acc[j].x, norm, base);
        tr[(2 * j + 1) * N_LABELS + my_lab] = fmaf(acc[j].y, norm, base);
    }
    __syncthreads();

    const float4* tr4 = (const float4*)tr;
    float4* out4 = (float4*)(out + (size_t)cell0 * N_LABELS);
    #pragma unroll
    for (int rr = 0; rr < CPB * N_LABELS / 4 / NTHREADS; ++rr)
        out4[t + rr * NTHREADS] = tr4[t + rr * NTHREADS];
}

// ---------------------------------------------------------------------------
// DIAGNOSTIC ROUND: main launched 3x (idempotent). With R4 = O + B + M and
// R5 = O + B + 3M  =>  M = (R5 - R4) / 2. No kernel-code changes vs round 4.
// ---------------------------------------------------------------------------
extern "C" void kernel_launch(void* const* d_in, const int* in_sizes, int n_in,
                              void* d_out, int out_size, void* d_ws, size_t ws_size,
                              hipStream_t stream)
{
    const float* z      = (const float*)d_in[0];  // (16384, 2)
    const float* dconst = (const float*)d_in[1];  // scalar
    const float* ex     = (const float*)d_in[2];  // (4096,)
    const float* ey     = (const float*)d_in[3];  // (4096,)
    const int*   labels = (const int*)d_in[4];    // (4096,)
    float*       out    = (float*)d_out;          // (16384, 512)

    float2* table = (float2*)d_ws;                                        // 48 KB
    int*    meta  = (int*)((char*)d_ws + (size_t)TABLE * sizeof(float2)); // 8 KB

    build_kernel<<<1, NTHREADS, 0, stream>>>(ex, ey, labels, dconst, table, meta);

    diffusion_main_kernel<<<N_CELLS / CPB, NTHREADS, 0, stream>>>(
        z, dconst, (const v2f*)table, meta, out);
    diffusion_main_kernel<<<N_CELLS / CPB, NTHREADS, 0, stream>>>(
        z, dconst, (const v2f*)table, meta, out);
    diffusion_main_kernel<<<N_CELLS / CPB, NTHREADS, 0, stream>>>(
        z, dconst, (const v2f*)table, meta, out);
}